// Round 5
// baseline (1552.741 us; speedup 1.0000x reference)
//
#include <hip/hip_runtime.h>

#define DIM 128

using f16 = _Float16;
using f16x4 = __attribute__((ext_vector_type(4))) f16;
using f32x4 = __attribute__((ext_vector_type(4))) float;

// ---------------- CSR build ----------------
// Round-3/4 post-mortem: direct scatter of adj (4B stores) ran at ~16x write
// amplification (168-195 MB for a 12 MB array) because a row's ~15 edges are
// uniformly spread across the edge stream — an adj line must survive in L2
// for the WHOLE kernel to write-combine, and it doesn't (XCD windowing alone
// didn't fix it: 195->168 MB only).
// Fix: two-phase binned scatter. Bins = aligned 256-row groups; since bins
// are contiguous row ranges, bin base offsets are just row_ptr[b<<8].
//  phase 1 (k_bin):   append packed (c<<8 | r&255) into the bin's segment.
//                     Frontier lines fill with 8 CONSECUTIVE appends (tight
//                     in time -> L2 write-combining works); XCD-windowed by
//                     (bin&7) so each frontier line is owned by one L2.
//  phase 2 (k_place): one block per bin; LDS cursors from row_ptr; scatter
//                     into the bin's contiguous ~10KB adj span (L2-hot).

__global__ void k_count(const int* __restrict__ u_idx, const int* __restrict__ i_idx,
                        int E, int n_u, int n, int* __restrict__ deg) {
    int grp = blockIdx.x & 7;
    int gb  = blockIdx.x >> 3;
    int ngb = gridDim.x >> 3;
    int lo = (int)((long long)n * grp / 8);
    int hi = (int)((long long)n * (grp + 1) / 8);
    int i = gb * blockDim.x + threadIdx.x;
    int stride = ngb * blockDim.x;
    for (; i < E; i += stride) {
        int u = __builtin_nontemporal_load(&u_idx[i]);
        int t = __builtin_nontemporal_load(&i_idx[i]) + n_u;
        if (u >= lo && u < hi) atomicAdd(&deg[u], 1);
        if (t >= lo && t < hi) atomicAdd(&deg[t], 1);
    }
}

// exclusive scan over deg (3 kernels, n up to 512*1024)
// scan1 also emits rnorm (free fusion: same pass over deg)
__global__ void k_scan1(const int* __restrict__ deg, int n, int* __restrict__ partials,
                        float* __restrict__ rnorm) {
    __shared__ int sh[256];
    int tid = threadIdx.x;
    int base = blockIdx.x * 1024 + tid * 4;
    int s = 0;
#pragma unroll
    for (int j = 0; j < 4; ++j) {
        int idx = base + j;
        if (idx < n) {
            int d = deg[idx];
            s += d;
            // reference deg = 2*d (bincount over [r,c]); rows with d==0 never feed edges
            rnorm[idx] = (d > 0) ? rsqrtf(2.0f * (float)d) : 0.0f;
        }
    }
    sh[tid] = s;
    __syncthreads();
    for (int off = 128; off > 0; off >>= 1) {
        if (tid < off) sh[tid] += sh[tid + off];
        __syncthreads();
    }
    if (tid == 0) partials[blockIdx.x] = sh[0];
}

__global__ void k_scan2(const int* __restrict__ partials, int* __restrict__ offsets, int NB) {
    __shared__ int sh[512];
    int tid = threadIdx.x;
    int v = (tid < NB) ? partials[tid] : 0;
    sh[tid] = v;
    __syncthreads();
    for (int off = 1; off < 512; off <<= 1) {
        int t = (tid >= off) ? sh[tid - off] : 0;
        __syncthreads();
        sh[tid] += t;
        __syncthreads();
    }
    if (tid < NB) offsets[tid] = sh[tid] - v;  // exclusive
}

__global__ void k_scan3(const int* __restrict__ deg, int n,
                        const int* __restrict__ offsets, int* __restrict__ row_ptr, int twoE) {
    __shared__ int sh[256];
    int tid = threadIdx.x;
    int base = blockIdx.x * 1024 + tid * 4;
    int v[4];
    int ts = 0;
#pragma unroll
    for (int j = 0; j < 4; ++j) {
        int idx = base + j;
        v[j] = (idx < n) ? deg[idx] : 0;
        ts += v[j];
    }
    sh[tid] = ts;
    __syncthreads();
    for (int off = 1; off < 256; off <<= 1) {
        int t = (tid >= off) ? sh[tid - off] : 0;
        __syncthreads();
        sh[tid] += t;
        __syncthreads();
    }
    int run = sh[tid] - ts + offsets[blockIdx.x];
#pragma unroll
    for (int j = 0; j < 4; ++j) {
        int idx = base + j;
        if (idx < n) row_ptr[idx] = run;
        run += v[j];
    }
    if (blockIdx.x == 0 && tid == 0) row_ptr[n] = twoE;
}

// phase 1: binned append. pre[] entry = (c << 8) | (r & 255)   (c < 2^19 ok
// for n = 300K; r&255 = row-local index within the 256-row bin).
// XCD-windowed by (bin & 7): each bin's append frontier owned by one L2.
__global__ void k_bin(const int* __restrict__ u_idx, const int* __restrict__ i_idx,
                      int E, int n_u, int n, const int* __restrict__ row_ptr,
                      int* __restrict__ bin_cur, unsigned* __restrict__ pre) {
    int grp = blockIdx.x & 7;
    int gb  = blockIdx.x >> 3;
    int ngb = gridDim.x >> 3;
    int i = gb * blockDim.x + threadIdx.x;
    int stride = ngb * blockDim.x;
    for (; i < E; i += stride) {
        int u = __builtin_nontemporal_load(&u_idx[i]);
        int t = __builtin_nontemporal_load(&i_idx[i]) + n_u;
        int bu = u >> 8, bt = t >> 8;
        if ((bu & 7) == grp) {
            int pos = atomicAdd(&bin_cur[bu], 1);
            pre[row_ptr[bu << 8] + pos] = ((unsigned)t << 8) | (unsigned)(u & 255);
        }
        if ((bt & 7) == grp) {
            int pos = atomicAdd(&bin_cur[bt], 1);
            pre[row_ptr[bt << 8] + pos] = ((unsigned)u << 8) | (unsigned)(t & 255);
        }
    }
}

// phase 2: per-bin placement. One block per bin; LDS row cursors seeded from
// row_ptr; sequential read of the bin's pre[] segment; scatter into the bin's
// contiguous adj span (stays hot in L2, evicts as full lines).
__global__ __launch_bounds__(256) void k_place(const int* __restrict__ row_ptr, int n,
                                               const unsigned* __restrict__ pre,
                                               int* __restrict__ adj) {
    __shared__ int cur[256];
    int b = blockIdx.x;
    int r0 = b << 8;
    int t = threadIdx.x;
    int rows = n - r0; if (rows > 256) rows = 256;
    if (t < rows) cur[t] = row_ptr[r0 + t];
    __syncthreads();
    int base = row_ptr[r0];
    int rend = r0 + 256; if (rend > n) rend = n;
    int end = row_ptr[rend];
    for (int i = base + t; i < end; i += 256) {
        unsigned p = __builtin_nontemporal_load(&pre[i]);
        int rl = (int)(p & 255u);
        int c  = (int)(p >> 8);
        int pos = atomicAdd(&cur[rl], 1);
        adj[pos] = c;
    }
}

// fp16 pre-scaled gather source: xh[v] = fp16(rnorm[v] * x0[v]).
// NT load of emb (streamed; re-read only much later in MODE-1),
// NORMAL store of xh (it is the gather table — must stay cache-resident).
__global__ void k_scale_h(const float* __restrict__ u_emb, const float* __restrict__ i_emb,
                          const float* __restrict__ rnorm, int n_u, int n,
                          f16* __restrict__ xh) {
    int g = blockIdx.x * blockDim.x + threadIdx.x;
    int stride = gridDim.x * blockDim.x;
    int total = n * 32;
    for (; g < total; g += stride) {
        int v = g >> 5;
        int lane = g & 31;
        const float* src = (v < n_u) ? (u_emb + (size_t)v * DIM)
                                     : (i_emb + (size_t)(v - n_u) * DIM);
        float r = rnorm[v];
        f32x4 x = __builtin_nontemporal_load(
            reinterpret_cast<const f32x4*>(src + lane * 4));
        f16x4 o;
        o[0] = (f16)(x[0] * r);
        o[1] = (f16)(x[1] * r);
        o[2] = (f16)(x[2] * r);
        o[3] = (f16)(x[3] * r);
        *reinterpret_cast<f16x4*>(xh + (size_t)v * DIM + lane * 4) = o;
    }
}

// ---------------- SpMM ----------------
// One 32-lane half-wave per row; 4 fp16 elements (8B) per lane (128 = 32*4).
// Gather source xh is ALWAYS pre-scaled by rnorm[c] (weights folded) -> no
// per-edge weight gather in either layer.
// MODE 0: writes yh[row] = fp16(rnorm[row]^2 * sum) = fp16(rnorm[row]*x1[row])
//         (the pre-scaled gather operand for layer 2) — NORMAL store (table).
// MODE 1: writes y[row] = (x0 + x1 + rnorm[row]*sum)/3, recovering
//         x1[row] = yh1[row]/rnorm[row] (deg-0 rows: x1 = 0, guarded).
//         x0 load + y store are NT (pure streams, keep L3 for the table).
// Tail is predicated with clamped indices so 4 gathers stay in flight
// (clamped duplicates hit the just-fetched L1 line — free).

template <int MODE>
__global__ __launch_bounds__(256) void k_spmm(const int* __restrict__ row_ptr,
                                              const int* __restrict__ adj,
                                              const float* __restrict__ rnorm,
                                              const f16* __restrict__ xh,
                                              const float* __restrict__ u_emb,
                                              const float* __restrict__ i_emb,
                                              int n_u, int n,
                                              float* __restrict__ y,
                                              f16* __restrict__ yh) {
    int g = blockIdx.x * blockDim.x + threadIdx.x;
    int row = g >> 5;
    int lane = g & 31;
    if (row >= n) return;
    int s = row_ptr[row];
    int e = row_ptr[row + 1];
    float rnr = rnorm[row];
    f32x4 acc = {0.f, 0.f, 0.f, 0.f};
    const f16* xb = xh + lane * 4;
    int e1 = e - 1;
    for (int k = s; k < e; k += 4) {
        int k1 = k + 1, k2 = k + 2, k3 = k + 3;
        int c0 = adj[k];
        int c1 = adj[(k1 <= e1) ? k1 : e1];
        int c2 = adj[(k2 <= e1) ? k2 : e1];
        int c3 = adj[(k3 <= e1) ? k3 : e1];
        float w1 = (k1 < e) ? 1.f : 0.f;
        float w2 = (k2 < e) ? 1.f : 0.f;
        float w3 = (k3 < e) ? 1.f : 0.f;
        f16x4 v0 = *reinterpret_cast<const f16x4*>(xb + (size_t)c0 * DIM);
        f16x4 v1 = *reinterpret_cast<const f16x4*>(xb + (size_t)c1 * DIM);
        f16x4 v2 = *reinterpret_cast<const f16x4*>(xb + (size_t)c2 * DIM);
        f16x4 v3 = *reinterpret_cast<const f16x4*>(xb + (size_t)c3 * DIM);
        acc[0] += (float)v0[0];
        acc[1] += (float)v0[1];
        acc[2] += (float)v0[2];
        acc[3] += (float)v0[3];
        acc[0] = fmaf((float)v1[0], w1, acc[0]);
        acc[1] = fmaf((float)v1[1], w1, acc[1]);
        acc[2] = fmaf((float)v1[2], w1, acc[2]);
        acc[3] = fmaf((float)v1[3], w1, acc[3]);
        acc[0] = fmaf((float)v2[0], w2, acc[0]);
        acc[1] = fmaf((float)v2[1], w2, acc[1]);
        acc[2] = fmaf((float)v2[2], w2, acc[2]);
        acc[3] = fmaf((float)v2[3], w2, acc[3]);
        acc[0] = fmaf((float)v3[0], w3, acc[0]);
        acc[1] = fmaf((float)v3[1], w3, acc[1]);
        acc[2] = fmaf((float)v3[2], w3, acc[2]);
        acc[3] = fmaf((float)v3[3], w3, acc[3]);
    }
    if (MODE == 0) {
        float sc = rnr * rnr;  // store rnorm[row] * x1[row]
        f16x4 h;
        h[0] = (f16)(acc[0] * sc);
        h[1] = (f16)(acc[1] * sc);
        h[2] = (f16)(acc[2] * sc);
        h[3] = (f16)(acc[3] * sc);
        *reinterpret_cast<f16x4*>(yh + (size_t)row * DIM + lane * 4) = h;
    } else {
        const float* x0b = (row < n_u) ? (u_emb + (size_t)row * DIM)
                                       : (i_emb + (size_t)(row - n_u) * DIM);
        f32x4 x0 = __builtin_nontemporal_load(
            reinterpret_cast<const f32x4*>(x0b + lane * 4));
        f16x4 a1 = *reinterpret_cast<const f16x4*>(xh + (size_t)row * DIM + lane * 4);
        float inv = (rnr > 0.f) ? (1.0f / rnr) : 0.f;  // x1 = a1/rnorm
        const float third = 1.0f / 3.0f;
        f32x4 o;
        o[0] = (x0[0] + (float)a1[0] * inv + acc[0] * rnr) * third;
        o[1] = (x0[1] + (float)a1[1] * inv + acc[1] * rnr) * third;
        o[2] = (x0[2] + (float)a1[2] * inv + acc[2] * rnr) * third;
        o[3] = (x0[3] + (float)a1[3] * inv + acc[3] * rnr) * third;
        __builtin_nontemporal_store(
            o, reinterpret_cast<f32x4*>(y + (size_t)row * DIM + lane * 4));
    }
}

// ---------------- host ----------------

static inline int grid_for(long long work, int block, int cap = 4096) {
    long long b = (work + block - 1) / block;
    if (b > cap) b = cap;
    if (b < 1) b = 1;
    return (int)b;
}

extern "C" void kernel_launch(void* const* d_in, const int* in_sizes, int n_in,
                              void* d_out, int out_size, void* d_ws, size_t ws_size,
                              hipStream_t stream) {
    const float* u_emb = (const float*)d_in[0];
    const float* i_emb = (const float*)d_in[1];
    const int* u_idx = (const int*)d_in[2];
    const int* i_idx = (const int*)d_in[3];

    const int n_u = in_sizes[0] / DIM;
    const int n_i = in_sizes[1] / DIM;
    const int n = n_u + n_i;
    const int E = in_sizes[2];
    const int twoE = 2 * E;
    const int NB = (n + 1023) / 1024;   // scan blocks (<= 512)
    const int NBIN = (n + 255) >> 8;    // 256-row bins

    // workspace layout
    char* w = (char*)d_ws;
    auto alloc = [&](size_t bytes) -> void* {
        void* p = (void*)w;
        w += (bytes + 255) & ~(size_t)255;
        return p;
    };
    f16*   xh0     = (f16*)alloc((size_t)n * DIM * sizeof(f16));  // rnorm-scaled x0, fp16
    f16*   xh1     = (f16*)alloc((size_t)n * DIM * sizeof(f16));  // rnorm-scaled x1, fp16
    float* rnorm   = (float*)alloc((size_t)n * sizeof(float));
    int*   degbin  = (int*)alloc((size_t)(n + NBIN) * sizeof(int));  // deg | bin_cur
    int*   deg     = degbin;
    int*   bin_cur = degbin + n;
    int*   row_ptr = (int*)alloc((size_t)(n + 1) * sizeof(int));
    int*   adj     = (int*)alloc((size_t)twoE * sizeof(int));
    int*   parts   = (int*)alloc((size_t)NB * sizeof(int));
    int*   offs    = (int*)alloc((size_t)NB * sizeof(int));
    // pre aliases xh1: written by k_bin, read by k_place — both complete
    // before spmm<0> writes xh1 (disjoint lifetimes, 12 MB < 77 MB).
    unsigned* pre  = (unsigned*)xh1;
    (void)ws_size;

    hipMemsetAsync(degbin, 0, (size_t)(n + NBIN) * sizeof(int), stream);

    // XCD-windowed scatters: grid multiple of 8 (blockIdx&7 -> XCD group)
    k_count<<<2048, 256, 0, stream>>>(u_idx, i_idx, E, n_u, n, deg);
    k_scan1<<<NB, 256, 0, stream>>>(deg, n, parts, rnorm);
    k_scan2<<<1, 512, 0, stream>>>(parts, offs, NB);
    k_scan3<<<NB, 256, 0, stream>>>(deg, n, offs, row_ptr, twoE);
    k_bin<<<2048, 256, 0, stream>>>(u_idx, i_idx, E, n_u, n, row_ptr, bin_cur, pre);
    k_place<<<NBIN, 256, 0, stream>>>(row_ptr, n, pre, adj);
    k_scale_h<<<grid_for((long long)n * 32, 256, 8192), 256, 0, stream>>>(u_emb, i_emb, rnorm,
                                                                          n_u, n, xh0);

    int sblocks = (int)(((long long)n * 32 + 255) / 256);
    // layer 1: xh1 = fp16( rnorm^2 * (A_unw @ xh0) ) = rnorm .* x1   (fp16)
    k_spmm<0><<<sblocks, 256, 0, stream>>>(row_ptr, adj, rnorm, xh0, nullptr, nullptr,
                                           n_u, n, nullptr, xh1);
    // layer 2 + fused combine: out = (x0 + xh1/rnorm + rnorm*(A_unw @ xh1))/3
    k_spmm<1><<<sblocks, 256, 0, stream>>>(row_ptr, adj, rnorm, xh1, u_emb, i_emb,
                                           n_u, n, (float*)d_out, nullptr);
}

// Round 6
// 1072.457 us; speedup vs baseline: 1.4478x; 1.4478x over previous
//
#include <hip/hip_runtime.h>

#define DIM 128

using f16 = _Float16;
using f16x4 = __attribute__((ext_vector_type(4))) f16;
using f32x4 = __attribute__((ext_vector_type(4))) float;

// ---------------- CSR build ----------------
// Round-3/4 post-mortem: direct scatter of adj (4B stores) runs at ~16x write
// amplification (168-195 MB for a 12 MB array): a row's ~15 edges are spread
// uniformly over the edge stream, so an adj line cannot survive in L2 long
// enough to write-combine.
// Fix: two-phase binned scatter. Bins = aligned 256-row groups; bin base
// offsets are just row_ptr[b<<8] (bins are contiguous row ranges).
//  phase 1 (k_bin):   append packed (c<<8 | r&255) into the bin's pre segment.
//                     Frontier lines fill with 8 temporally-adjacent appends
//                     -> L2 write-combining works.
//  phase 2 (k_place): one block per bin; LDS cursors from row_ptr; scatter
//                     into the bin's contiguous ~10KB adj span (L2-hot).
// Round-5 post-mortem: bin ownership MUST be contiguous, NOT interleaved by
// (bin&7) — 16 int counters share a 64B line, and interleaving made every
// counter line atomically contended by all 8 XCDs (exclusive-ownership
// migration per atomic -> 1094 us, everything idle). Contiguous 16-aligned
// windows give each XCD group private counter lines (same reason k_count's
// contiguous row windows always behaved).

__global__ void k_count(const int* __restrict__ u_idx, const int* __restrict__ i_idx,
                        int E, int n_u, int n, int* __restrict__ deg) {
    int grp = blockIdx.x & 7;
    int gb  = blockIdx.x >> 3;
    int ngb = gridDim.x >> 3;
    int lo = (int)((long long)n * grp / 8);
    int hi = (int)((long long)n * (grp + 1) / 8);
    int i = gb * blockDim.x + threadIdx.x;
    int stride = ngb * blockDim.x;
    for (; i < E; i += stride) {
        int u = __builtin_nontemporal_load(&u_idx[i]);
        int t = __builtin_nontemporal_load(&i_idx[i]) + n_u;
        if (u >= lo && u < hi) atomicAdd(&deg[u], 1);
        if (t >= lo && t < hi) atomicAdd(&deg[t], 1);
    }
}

// exclusive scan over deg (3 kernels, n up to 512*1024)
// scan1 also emits rnorm (free fusion: same pass over deg)
__global__ void k_scan1(const int* __restrict__ deg, int n, int* __restrict__ partials,
                        float* __restrict__ rnorm) {
    __shared__ int sh[256];
    int tid = threadIdx.x;
    int base = blockIdx.x * 1024 + tid * 4;
    int s = 0;
#pragma unroll
    for (int j = 0; j < 4; ++j) {
        int idx = base + j;
        if (idx < n) {
            int d = deg[idx];
            s += d;
            // reference deg = 2*d (bincount over [r,c]); rows with d==0 never feed edges
            rnorm[idx] = (d > 0) ? rsqrtf(2.0f * (float)d) : 0.0f;
        }
    }
    sh[tid] = s;
    __syncthreads();
    for (int off = 128; off > 0; off >>= 1) {
        if (tid < off) sh[tid] += sh[tid + off];
        __syncthreads();
    }
    if (tid == 0) partials[blockIdx.x] = sh[0];
}

__global__ void k_scan2(const int* __restrict__ partials, int* __restrict__ offsets, int NB) {
    __shared__ int sh[512];
    int tid = threadIdx.x;
    int v = (tid < NB) ? partials[tid] : 0;
    sh[tid] = v;
    __syncthreads();
    for (int off = 1; off < 512; off <<= 1) {
        int t = (tid >= off) ? sh[tid - off] : 0;
        __syncthreads();
        sh[tid] += t;
        __syncthreads();
    }
    if (tid < NB) offsets[tid] = sh[tid] - v;  // exclusive
}

__global__ void k_scan3(const int* __restrict__ deg, int n,
                        const int* __restrict__ offsets, int* __restrict__ row_ptr, int twoE) {
    __shared__ int sh[256];
    int tid = threadIdx.x;
    int base = blockIdx.x * 1024 + tid * 4;
    int v[4];
    int ts = 0;
#pragma unroll
    for (int j = 0; j < 4; ++j) {
        int idx = base + j;
        v[j] = (idx < n) ? deg[idx] : 0;
        ts += v[j];
    }
    sh[tid] = ts;
    __syncthreads();
    for (int off = 1; off < 256; off <<= 1) {
        int t = (tid >= off) ? sh[tid - off] : 0;
        __syncthreads();
        sh[tid] += t;
        __syncthreads();
    }
    int run = sh[tid] - ts + offsets[blockIdx.x];
#pragma unroll
    for (int j = 0; j < 4; ++j) {
        int idx = base + j;
        if (idx < n) row_ptr[idx] = run;
        run += v[j];
    }
    if (blockIdx.x == 0 && tid == 0) row_ptr[n] = twoE;
}

// phase 1: binned append. pre[] entry = (c << 8) | (r & 255)   (c < 2^19 ok
// for n = 300K; r&255 = row-local index within the 256-row bin).
// Bin ownership: CONTIGUOUS 16-aligned windows per XCD group (see header).
__global__ void k_bin(const int* __restrict__ u_idx, const int* __restrict__ i_idx,
                      int E, int n_u, int n, int NBIN, int GSZ,
                      const int* __restrict__ row_ptr,
                      int* __restrict__ bin_cur, unsigned* __restrict__ pre) {
    int grp = blockIdx.x & 7;
    int gb  = blockIdx.x >> 3;
    int ngb = gridDim.x >> 3;
    int b0 = grp * GSZ;
    int b1 = b0 + GSZ; if (b1 > NBIN) b1 = NBIN;
    int i = gb * blockDim.x + threadIdx.x;
    int stride = ngb * blockDim.x;
    for (; i < E; i += stride) {
        int u = __builtin_nontemporal_load(&u_idx[i]);
        int t = __builtin_nontemporal_load(&i_idx[i]) + n_u;
        int bu = u >> 8, bt = t >> 8;
        if (bu >= b0 && bu < b1) {
            int pos = atomicAdd(&bin_cur[bu], 1);
            pre[row_ptr[bu << 8] + pos] = ((unsigned)t << 8) | (unsigned)(u & 255);
        }
        if (bt >= b0 && bt < b1) {
            int pos = atomicAdd(&bin_cur[bt], 1);
            pre[row_ptr[bt << 8] + pos] = ((unsigned)u << 8) | (unsigned)(t & 255);
        }
    }
}

// phase 2: per-bin placement. One block per bin; LDS row cursors seeded from
// row_ptr; sequential read of the bin's pre[] segment; scatter into the bin's
// contiguous adj span (stays hot in L2, evicts as full lines).
__global__ __launch_bounds__(256) void k_place(const int* __restrict__ row_ptr, int n,
                                               const unsigned* __restrict__ pre,
                                               int* __restrict__ adj) {
    __shared__ int cur[256];
    int b = blockIdx.x;
    int r0 = b << 8;
    int t = threadIdx.x;
    int rows = n - r0; if (rows > 256) rows = 256;
    if (t < rows) cur[t] = row_ptr[r0 + t];
    __syncthreads();
    int base = row_ptr[r0];
    int rend = r0 + 256; if (rend > n) rend = n;
    int end = row_ptr[rend];
    for (int i = base + t; i < end; i += 256) {
        unsigned p = __builtin_nontemporal_load(&pre[i]);
        int rl = (int)(p & 255u);
        int c  = (int)(p >> 8);
        int pos = atomicAdd(&cur[rl], 1);
        adj[pos] = c;
    }
}

// fp16 pre-scaled gather source: xh[v] = fp16(rnorm[v] * x0[v]).
// NT load of emb (streamed; re-read only much later in MODE-1),
// NORMAL store of xh (it is the gather table — must stay cache-resident).
__global__ void k_scale_h(const float* __restrict__ u_emb, const float* __restrict__ i_emb,
                          const float* __restrict__ rnorm, int n_u, int n,
                          f16* __restrict__ xh) {
    int g = blockIdx.x * blockDim.x + threadIdx.x;
    int stride = gridDim.x * blockDim.x;
    int total = n * 32;
    for (; g < total; g += stride) {
        int v = g >> 5;
        int lane = g & 31;
        const float* src = (v < n_u) ? (u_emb + (size_t)v * DIM)
                                     : (i_emb + (size_t)(v - n_u) * DIM);
        float r = rnorm[v];
        f32x4 x = __builtin_nontemporal_load(
            reinterpret_cast<const f32x4*>(src + lane * 4));
        f16x4 o;
        o[0] = (f16)(x[0] * r);
        o[1] = (f16)(x[1] * r);
        o[2] = (f16)(x[2] * r);
        o[3] = (f16)(x[3] * r);
        *reinterpret_cast<f16x4*>(xh + (size_t)v * DIM + lane * 4) = o;
    }
}

// ---------------- SpMM ----------------
// One 32-lane half-wave per row; 4 fp16 elements (8B) per lane (128 = 32*4).
// Gather source xh is ALWAYS pre-scaled by rnorm[c] (weights folded) -> no
// per-edge weight gather in either layer.
// MODE 0: writes yh[row] = fp16(rnorm[row]^2 * sum) = fp16(rnorm[row]*x1[row])
//         (the pre-scaled gather operand for layer 2) — NORMAL store (table).
// MODE 1: writes y[row] = (x0 + x1 + rnorm[row]*sum)/3, recovering
//         x1[row] = yh1[row]/rnorm[row] (deg-0 rows: x1 = 0, guarded).
//         x0 load + y store are NT (pure streams, keep L3 for the table).
// Tail is predicated with clamped indices so 4 gathers stay in flight
// (clamped duplicates hit the just-fetched L1 line — free).

template <int MODE>
__global__ __launch_bounds__(256) void k_spmm(const int* __restrict__ row_ptr,
                                              const int* __restrict__ adj,
                                              const float* __restrict__ rnorm,
                                              const f16* __restrict__ xh,
                                              const float* __restrict__ u_emb,
                                              const float* __restrict__ i_emb,
                                              int n_u, int n,
                                              float* __restrict__ y,
                                              f16* __restrict__ yh) {
    int g = blockIdx.x * blockDim.x + threadIdx.x;
    int row = g >> 5;
    int lane = g & 31;
    if (row >= n) return;
    int s = row_ptr[row];
    int e = row_ptr[row + 1];
    float rnr = rnorm[row];
    f32x4 acc = {0.f, 0.f, 0.f, 0.f};
    const f16* xb = xh + lane * 4;
    int e1 = e - 1;
    for (int k = s; k < e; k += 4) {
        int k1 = k + 1, k2 = k + 2, k3 = k + 3;
        int c0 = adj[k];
        int c1 = adj[(k1 <= e1) ? k1 : e1];
        int c2 = adj[(k2 <= e1) ? k2 : e1];
        int c3 = adj[(k3 <= e1) ? k3 : e1];
        float w1 = (k1 < e) ? 1.f : 0.f;
        float w2 = (k2 < e) ? 1.f : 0.f;
        float w3 = (k3 < e) ? 1.f : 0.f;
        f16x4 v0 = *reinterpret_cast<const f16x4*>(xb + (size_t)c0 * DIM);
        f16x4 v1 = *reinterpret_cast<const f16x4*>(xb + (size_t)c1 * DIM);
        f16x4 v2 = *reinterpret_cast<const f16x4*>(xb + (size_t)c2 * DIM);
        f16x4 v3 = *reinterpret_cast<const f16x4*>(xb + (size_t)c3 * DIM);
        acc[0] += (float)v0[0];
        acc[1] += (float)v0[1];
        acc[2] += (float)v0[2];
        acc[3] += (float)v0[3];
        acc[0] = fmaf((float)v1[0], w1, acc[0]);
        acc[1] = fmaf((float)v1[1], w1, acc[1]);
        acc[2] = fmaf((float)v1[2], w1, acc[2]);
        acc[3] = fmaf((float)v1[3], w1, acc[3]);
        acc[0] = fmaf((float)v2[0], w2, acc[0]);
        acc[1] = fmaf((float)v2[1], w2, acc[1]);
        acc[2] = fmaf((float)v2[2], w2, acc[2]);
        acc[3] = fmaf((float)v2[3], w2, acc[3]);
        acc[0] = fmaf((float)v3[0], w3, acc[0]);
        acc[1] = fmaf((float)v3[1], w3, acc[1]);
        acc[2] = fmaf((float)v3[2], w3, acc[2]);
        acc[3] = fmaf((float)v3[3], w3, acc[3]);
    }
    if (MODE == 0) {
        float sc = rnr * rnr;  // store rnorm[row] * x1[row]
        f16x4 h;
        h[0] = (f16)(acc[0] * sc);
        h[1] = (f16)(acc[1] * sc);
        h[2] = (f16)(acc[2] * sc);
        h[3] = (f16)(acc[3] * sc);
        *reinterpret_cast<f16x4*>(yh + (size_t)row * DIM + lane * 4) = h;
    } else {
        const float* x0b = (row < n_u) ? (u_emb + (size_t)row * DIM)
                                       : (i_emb + (size_t)(row - n_u) * DIM);
        f32x4 x0 = __builtin_nontemporal_load(
            reinterpret_cast<const f32x4*>(x0b + lane * 4));
        f16x4 a1 = *reinterpret_cast<const f16x4*>(xh + (size_t)row * DIM + lane * 4);
        float inv = (rnr > 0.f) ? (1.0f / rnr) : 0.f;  // x1 = a1/rnorm
        const float third = 1.0f / 3.0f;
        f32x4 o;
        o[0] = (x0[0] + (float)a1[0] * inv + acc[0] * rnr) * third;
        o[1] = (x0[1] + (float)a1[1] * inv + acc[1] * rnr) * third;
        o[2] = (x0[2] + (float)a1[2] * inv + acc[2] * rnr) * third;
        o[3] = (x0[3] + (float)a1[3] * inv + acc[3] * rnr) * third;
        __builtin_nontemporal_store(
            o, reinterpret_cast<f32x4*>(y + (size_t)row * DIM + lane * 4));
    }
}

// ---------------- host ----------------

static inline int grid_for(long long work, int block, int cap = 4096) {
    long long b = (work + block - 1) / block;
    if (b > cap) b = cap;
    if (b < 1) b = 1;
    return (int)b;
}

extern "C" void kernel_launch(void* const* d_in, const int* in_sizes, int n_in,
                              void* d_out, int out_size, void* d_ws, size_t ws_size,
                              hipStream_t stream) {
    const float* u_emb = (const float*)d_in[0];
    const float* i_emb = (const float*)d_in[1];
    const int* u_idx = (const int*)d_in[2];
    const int* i_idx = (const int*)d_in[3];

    const int n_u = in_sizes[0] / DIM;
    const int n_i = in_sizes[1] / DIM;
    const int n = n_u + n_i;
    const int E = in_sizes[2];
    const int twoE = 2 * E;
    const int NB = (n + 1023) / 1024;   // scan blocks (<= 512)
    const int NBIN = (n + 255) >> 8;    // 256-row bins
    // bins per XCD group: contiguous, rounded up to 16 (one 64B line of
    // counters) so no counter line is shared across groups
    const int GSZ = (((NBIN + 7) / 8) + 15) & ~15;

    // workspace layout
    char* w = (char*)d_ws;
    auto alloc = [&](size_t bytes) -> void* {
        void* p = (void*)w;
        w += (bytes + 255) & ~(size_t)255;
        return p;
    };
    f16*   xh0     = (f16*)alloc((size_t)n * DIM * sizeof(f16));  // rnorm-scaled x0, fp16
    f16*   xh1     = (f16*)alloc((size_t)n * DIM * sizeof(f16));  // rnorm-scaled x1, fp16
    float* rnorm   = (float*)alloc((size_t)n * sizeof(float));
    int*   degbin  = (int*)alloc((size_t)(n + NBIN) * sizeof(int));  // deg | bin_cur
    int*   deg     = degbin;
    int*   bin_cur = degbin + n;
    int*   row_ptr = (int*)alloc((size_t)(n + 1) * sizeof(int));
    int*   adj     = (int*)alloc((size_t)twoE * sizeof(int));
    int*   parts   = (int*)alloc((size_t)NB * sizeof(int));
    int*   offs    = (int*)alloc((size_t)NB * sizeof(int));
    // pre aliases xh1: written by k_bin, read by k_place — both complete
    // before spmm<0> writes xh1 (disjoint lifetimes, 12 MB < 77 MB).
    unsigned* pre  = (unsigned*)xh1;
    (void)ws_size;

    hipMemsetAsync(degbin, 0, (size_t)(n + NBIN) * sizeof(int), stream);

    // XCD-windowed scatters: grid multiple of 8 (blockIdx&7 -> XCD group)
    k_count<<<2048, 256, 0, stream>>>(u_idx, i_idx, E, n_u, n, deg);
    k_scan1<<<NB, 256, 0, stream>>>(deg, n, parts, rnorm);
    k_scan2<<<1, 512, 0, stream>>>(parts, offs, NB);
    k_scan3<<<NB, 256, 0, stream>>>(deg, n, offs, row_ptr, twoE);
    k_bin<<<2048, 256, 0, stream>>>(u_idx, i_idx, E, n_u, n, NBIN, GSZ,
                                    row_ptr, bin_cur, pre);
    k_place<<<NBIN, 256, 0, stream>>>(row_ptr, n, pre, adj);
    k_scale_h<<<grid_for((long long)n * 32, 256, 8192), 256, 0, stream>>>(u_emb, i_emb, rnorm,
                                                                          n_u, n, xh0);

    int sblocks = (int)(((long long)n * 32 + 255) / 256);
    // layer 1: xh1 = fp16( rnorm^2 * (A_unw @ xh0) ) = rnorm .* x1   (fp16)
    k_spmm<0><<<sblocks, 256, 0, stream>>>(row_ptr, adj, rnorm, xh0, nullptr, nullptr,
                                           n_u, n, nullptr, xh1);
    // layer 2 + fused combine: out = (x0 + xh1/rnorm + rnorm*(A_unw @ xh1))/3
    k_spmm<1><<<sblocks, 256, 0, stream>>>(row_ptr, adj, rnorm, xh1, u_emb, i_emb,
                                           n_u, n, (float*)d_out, nullptr);
}

// Round 7
// 379.274 us; speedup vs baseline: 4.0940x; 2.8277x over previous
//
#include <hip/hip_runtime.h>

#define DIM 128
#define NBLK 256        // edge-partition blocks for hist/scatter (must match)
#define BKT_BITS 9      // 512 rows per bucket
#define BKT_ROWS 512
#define MAXBUK 1024     // supports n up to 512K rows

using f16 = _Float16;
using f16x4 = __attribute__((ext_vector_type(4))) f16;
using f32x4 = __attribute__((ext_vector_type(4))) float;

// ---------------- CSR build: atomic-free counting sort ----------------
// History: direct scatter = 16x write amplification (rounds 3-4, 168-195 MB
// for 12 MB adj: row's edges spread over whole stream, lines can't survive
// in L2 to combine). Global-atomic binning = atomic-latency-bound disaster
// (rounds 5-6: 3M global atomicAdds with dependent stores ~= 5 atomics/us).
// This build has ZERO global atomics: all positions precomputed by scans;
// stores are fire-and-forget and temporally clustered per (block,bucket).

// same-XCD blocks get adjacent output sub-ranges inside each bucket, so
// range-boundary cache lines are shared only within one XCD's L2
__device__ __forceinline__ int permb(int b) { return ((b & 7) << 5) | (b >> 3); }

// pass 1: per-block LDS histogram over 512-row buckets (both edge endpoints)
__global__ __launch_bounds__(256) void k_hist(const int* __restrict__ u_idx,
                                              const int* __restrict__ i_idx,
                                              int E, int n_u, int NBUK,
                                              int* __restrict__ hist) {
    __shared__ int h[MAXBUK];
    int b = blockIdx.x, tid = threadIdx.x;
    for (int j = tid; j < NBUK; j += 256) h[j] = 0;
    __syncthreads();
    int chunk = (E + NBLK - 1) / NBLK;
    int i0 = b * chunk, i1 = E < i0 + chunk ? E : i0 + chunk;
    for (int i = i0 + tid; i < i1; i += 256) {
        int u = __builtin_nontemporal_load(&u_idx[i]);
        int t = __builtin_nontemporal_load(&i_idx[i]) + n_u;
        atomicAdd(&h[u >> BKT_BITS], 1);
        atomicAdd(&h[t >> BKT_BITS], 1);
    }
    __syncthreads();
    int pb = permb(b);
    for (int j = tid; j < NBUK; j += 256) hist[j * NBLK + pb] = h[j];
}

// pass 2a: per-bucket exclusive scan over the 256 block counts (in place);
// bucket total goes to bb[k]
__global__ __launch_bounds__(256) void k_scanB(int* __restrict__ hist,
                                               int* __restrict__ bb) {
    __shared__ int sh[256];
    int k = blockIdx.x, t = threadIdx.x;
    int v = hist[k * NBLK + t];
    sh[t] = v;
    __syncthreads();
    for (int off = 1; off < 256; off <<= 1) {
        int tmp = (t >= off) ? sh[t - off] : 0;
        __syncthreads();
        sh[t] += tmp;
        __syncthreads();
    }
    hist[k * NBLK + t] = sh[t] - v;  // exclusive over (permuted) blocks
    if (t == 255) bb[k] = sh[255];   // bucket total
}

// pass 2b: exclusive scan of bucket totals -> bucket bases; bb[NBUK] = 2E
__global__ __launch_bounds__(1024) void k_scanT(int* __restrict__ bb, int NBUK) {
    __shared__ int sh[1024];
    int t = threadIdx.x;
    int v = (t < NBUK) ? bb[t] : 0;
    sh[t] = v;
    __syncthreads();
    for (int off = 1; off < 1024; off <<= 1) {
        int tmp = (t >= off) ? sh[t - off] : 0;
        __syncthreads();
        sh[t] += tmp;
        __syncthreads();
    }
    if (t < NBUK) bb[t] = sh[t] - v;
    if (t == NBUK - 1) bb[NBUK] = sh[t];
}

// pass 3: deterministic scatter into bucket-major pre[]. Entry = (c<<9 | r&511)
// (c < 2^19 ok for n=300K). Only LDS atomics (intra-block ranking); each
// (block,bucket) range ~80 B written back-to-back -> L2 write-combining.
__global__ __launch_bounds__(256) void k_scatter(const int* __restrict__ u_idx,
                                                 const int* __restrict__ i_idx,
                                                 int E, int n_u, int NBUK,
                                                 const int* __restrict__ hist,
                                                 const int* __restrict__ bb,
                                                 unsigned* __restrict__ pre) {
    __shared__ int boff[MAXBUK];
    __shared__ int cnt[MAXBUK];
    int b = blockIdx.x, tid = threadIdx.x;
    int pb = permb(b);
    for (int j = tid; j < NBUK; j += 256) {
        boff[j] = bb[j] + hist[j * NBLK + pb];
        cnt[j] = 0;
    }
    __syncthreads();
    int chunk = (E + NBLK - 1) / NBLK;
    int i0 = b * chunk, i1 = E < i0 + chunk ? E : i0 + chunk;
    for (int i = i0 + tid; i < i1; i += 256) {
        int u = __builtin_nontemporal_load(&u_idx[i]);
        int t = __builtin_nontemporal_load(&i_idx[i]) + n_u;
        int ku = u >> BKT_BITS, kt = t >> BKT_BITS;
        int p1 = atomicAdd(&cnt[ku], 1);
        pre[boff[ku] + p1] = ((unsigned)t << BKT_BITS) | (unsigned)(u & (BKT_ROWS - 1));
        int p2 = atomicAdd(&cnt[kt], 1);
        pre[boff[kt] + p2] = ((unsigned)u << BKT_BITS) | (unsigned)(t & (BKT_ROWS - 1));
    }
}

// pass 4: one block per bucket. Builds row_ptr for its 512 rows from the
// bucket's own entries (LDS histogram + pair-scan), then places into the
// bucket's contiguous ~20KB adj span (single-XCD L2-hot, full-line evicts).
// This also replaces the old k_count + 3-kernel global scan entirely.
__global__ __launch_bounds__(256) void k_place(const int* __restrict__ bb, int n,
                                               const unsigned* __restrict__ pre,
                                               int* __restrict__ row_ptr,
                                               int* __restrict__ adj) {
    __shared__ int cnt[BKT_ROWS];
    __shared__ int cur[BKT_ROWS];
    __shared__ int ps[256];
    int b = blockIdx.x, t = threadIdx.x;
    int r0 = b << BKT_BITS;
    int base = bb[b], end = bb[b + 1];
    cnt[t] = 0;
    cnt[t + 256] = 0;
    __syncthreads();
    for (int i = base + t; i < end; i += 256)
        atomicAdd(&cnt[pre[i] & (BKT_ROWS - 1)], 1);
    __syncthreads();
    // exclusive scan over 512 rows via pair-sums (256-wide Hillis-Steele)
    int a0 = cnt[2 * t], a1 = cnt[2 * t + 1];
    int pv = a0 + a1;
    ps[t] = pv;
    __syncthreads();
    for (int off = 1; off < 256; off <<= 1) {
        int tmp = (t >= off) ? ps[t - off] : 0;
        __syncthreads();
        ps[t] += tmp;
        __syncthreads();
    }
    int ex = ps[t] - pv;        // elems before row 2t
    int e0 = base + ex;         // start of row 2t
    int e1 = e0 + a0;           // start of row 2t+1
    cur[2 * t] = e0;
    cur[2 * t + 1] = e1;
    int rows = n - r0; if (rows > BKT_ROWS) rows = BKT_ROWS;
    if (2 * t < rows)     row_ptr[r0 + 2 * t] = e0;
    if (2 * t + 1 < rows) row_ptr[r0 + 2 * t + 1] = e1;
    if (t == 0 && r0 + BKT_ROWS >= n) row_ptr[n] = end;
    __syncthreads();
    for (int i = base + t; i < end; i += 256) {
        unsigned p = pre[i];  // L2-hot from pass A
        int rl = (int)(p & (BKT_ROWS - 1));
        int c = (int)(p >> BKT_BITS);
        int pos = atomicAdd(&cur[rl], 1);
        adj[pos] = c;
    }
}

// fp16 pre-scaled gather source: xh[v] = fp16(rnorm[v] * x0[v]).
// rnorm derived from row_ptr (deg = row length) and emitted as side output.
// NT load of emb (streamed); NORMAL store of xh (gather table, cache-resident).
__global__ void k_scale_h(const float* __restrict__ u_emb, const float* __restrict__ i_emb,
                          const int* __restrict__ row_ptr, float* __restrict__ rnorm,
                          int n_u, int n, f16* __restrict__ xh) {
    int g = blockIdx.x * blockDim.x + threadIdx.x;
    int stride = gridDim.x * blockDim.x;
    int total = n * 32;
    for (; g < total; g += stride) {
        int v = g >> 5;
        int lane = g & 31;
        int d = row_ptr[v + 1] - row_ptr[v];
        // reference deg = 2*d (bincount over [r,c]); d==0 rows never feed edges
        float r = (d > 0) ? rsqrtf(2.0f * (float)d) : 0.0f;
        if (lane == 0) rnorm[v] = r;
        const float* src = (v < n_u) ? (u_emb + (size_t)v * DIM)
                                     : (i_emb + (size_t)(v - n_u) * DIM);
        f32x4 x = __builtin_nontemporal_load(
            reinterpret_cast<const f32x4*>(src + lane * 4));
        f16x4 o;
        o[0] = (f16)(x[0] * r);
        o[1] = (f16)(x[1] * r);
        o[2] = (f16)(x[2] * r);
        o[3] = (f16)(x[3] * r);
        *reinterpret_cast<f16x4*>(xh + (size_t)v * DIM + lane * 4) = o;
    }
}

// ---------------- SpMM ----------------
// One 32-lane half-wave per row; 4 fp16 elements (8B) per lane (128 = 32*4).
// Gather source xh is ALWAYS pre-scaled by rnorm[c] (weights folded).
// MODE 0: writes yh[row] = fp16(rnorm[row]^2 * sum) = fp16(rnorm[row]*x1[row])
//         (pre-scaled gather operand for layer 2) — NORMAL store (table).
// MODE 1: writes y[row] = (x0 + x1 + rnorm[row]*sum)/3, recovering
//         x1[row] = yh1[row]/rnorm[row] (deg-0 rows: x1 = 0, guarded).
//         x0 load + y store are NT (pure streams, keep L3 for the table).
// Tail is predicated with clamped indices so 4 gathers stay in flight.

template <int MODE>
__global__ __launch_bounds__(256) void k_spmm(const int* __restrict__ row_ptr,
                                              const int* __restrict__ adj,
                                              const float* __restrict__ rnorm,
                                              const f16* __restrict__ xh,
                                              const float* __restrict__ u_emb,
                                              const float* __restrict__ i_emb,
                                              int n_u, int n,
                                              float* __restrict__ y,
                                              f16* __restrict__ yh) {
    int g = blockIdx.x * blockDim.x + threadIdx.x;
    int row = g >> 5;
    int lane = g & 31;
    if (row >= n) return;
    int s = row_ptr[row];
    int e = row_ptr[row + 1];
    float rnr = rnorm[row];
    f32x4 acc = {0.f, 0.f, 0.f, 0.f};
    const f16* xb = xh + lane * 4;
    int e1 = e - 1;
    for (int k = s; k < e; k += 4) {
        int k1 = k + 1, k2 = k + 2, k3 = k + 3;
        int c0 = adj[k];
        int c1 = adj[(k1 <= e1) ? k1 : e1];
        int c2 = adj[(k2 <= e1) ? k2 : e1];
        int c3 = adj[(k3 <= e1) ? k3 : e1];
        float w1 = (k1 < e) ? 1.f : 0.f;
        float w2 = (k2 < e) ? 1.f : 0.f;
        float w3 = (k3 < e) ? 1.f : 0.f;
        f16x4 v0 = *reinterpret_cast<const f16x4*>(xb + (size_t)c0 * DIM);
        f16x4 v1 = *reinterpret_cast<const f16x4*>(xb + (size_t)c1 * DIM);
        f16x4 v2 = *reinterpret_cast<const f16x4*>(xb + (size_t)c2 * DIM);
        f16x4 v3 = *reinterpret_cast<const f16x4*>(xb + (size_t)c3 * DIM);
        acc[0] += (float)v0[0];
        acc[1] += (float)v0[1];
        acc[2] += (float)v0[2];
        acc[3] += (float)v0[3];
        acc[0] = fmaf((float)v1[0], w1, acc[0]);
        acc[1] = fmaf((float)v1[1], w1, acc[1]);
        acc[2] = fmaf((float)v1[2], w1, acc[2]);
        acc[3] = fmaf((float)v1[3], w1, acc[3]);
        acc[0] = fmaf((float)v2[0], w2, acc[0]);
        acc[1] = fmaf((float)v2[1], w2, acc[1]);
        acc[2] = fmaf((float)v2[2], w2, acc[2]);
        acc[3] = fmaf((float)v2[3], w2, acc[3]);
        acc[0] = fmaf((float)v3[0], w3, acc[0]);
        acc[1] = fmaf((float)v3[1], w3, acc[1]);
        acc[2] = fmaf((float)v3[2], w3, acc[2]);
        acc[3] = fmaf((float)v3[3], w3, acc[3]);
    }
    if (MODE == 0) {
        float sc = rnr * rnr;  // store rnorm[row] * x1[row]
        f16x4 h;
        h[0] = (f16)(acc[0] * sc);
        h[1] = (f16)(acc[1] * sc);
        h[2] = (f16)(acc[2] * sc);
        h[3] = (f16)(acc[3] * sc);
        *reinterpret_cast<f16x4*>(yh + (size_t)row * DIM + lane * 4) = h;
    } else {
        const float* x0b = (row < n_u) ? (u_emb + (size_t)row * DIM)
                                       : (i_emb + (size_t)(row - n_u) * DIM);
        f32x4 x0 = __builtin_nontemporal_load(
            reinterpret_cast<const f32x4*>(x0b + lane * 4));
        f16x4 a1 = *reinterpret_cast<const f16x4*>(xh + (size_t)row * DIM + lane * 4);
        float inv = (rnr > 0.f) ? (1.0f / rnr) : 0.f;  // x1 = a1/rnorm
        const float third = 1.0f / 3.0f;
        f32x4 o;
        o[0] = (x0[0] + (float)a1[0] * inv + acc[0] * rnr) * third;
        o[1] = (x0[1] + (float)a1[1] * inv + acc[1] * rnr) * third;
        o[2] = (x0[2] + (float)a1[2] * inv + acc[2] * rnr) * third;
        o[3] = (x0[3] + (float)a1[3] * inv + acc[3] * rnr) * third;
        __builtin_nontemporal_store(
            o, reinterpret_cast<f32x4*>(y + (size_t)row * DIM + lane * 4));
    }
}

// ---------------- host ----------------

static inline int grid_for(long long work, int block, int cap = 4096) {
    long long b = (work + block - 1) / block;
    if (b > cap) b = cap;
    if (b < 1) b = 1;
    return (int)b;
}

extern "C" void kernel_launch(void* const* d_in, const int* in_sizes, int n_in,
                              void* d_out, int out_size, void* d_ws, size_t ws_size,
                              hipStream_t stream) {
    const float* u_emb = (const float*)d_in[0];
    const float* i_emb = (const float*)d_in[1];
    const int* u_idx = (const int*)d_in[2];
    const int* i_idx = (const int*)d_in[3];

    const int n_u = in_sizes[0] / DIM;
    const int n_i = in_sizes[1] / DIM;
    const int n = n_u + n_i;
    const int E = in_sizes[2];
    const int twoE = 2 * E;
    const int NBUK = (n + BKT_ROWS - 1) >> BKT_BITS;  // <= MAXBUK for n <= 512K

    // workspace layout
    char* w = (char*)d_ws;
    auto alloc = [&](size_t bytes) -> void* {
        void* p = (void*)w;
        w += (bytes + 255) & ~(size_t)255;
        return p;
    };
    f16*   xh0     = (f16*)alloc((size_t)n * DIM * sizeof(f16));  // rnorm-scaled x0, fp16
    f16*   xh1     = (f16*)alloc((size_t)n * DIM * sizeof(f16));  // rnorm-scaled x1, fp16
    float* rnorm   = (float*)alloc((size_t)n * sizeof(float));
    int*   row_ptr = (int*)alloc((size_t)(n + 1) * sizeof(int));
    int*   adj     = (int*)alloc((size_t)twoE * sizeof(int));
    int*   hist    = (int*)alloc((size_t)NBUK * NBLK * sizeof(int));
    int*   bb      = (int*)alloc((size_t)(NBUK + 1) * sizeof(int));
    // pre aliases xh1: written by k_scatter, read by k_place — both complete
    // before spmm<0> writes xh1 (disjoint lifetimes, 12 MB < 77 MB).
    unsigned* pre  = (unsigned*)xh1;
    (void)ws_size;

    // atomic-free CSR build (no memset needed anywhere)
    k_hist<<<NBLK, 256, 0, stream>>>(u_idx, i_idx, E, n_u, NBUK, hist);
    k_scanB<<<NBUK, 256, 0, stream>>>(hist, bb);
    k_scanT<<<1, 1024, 0, stream>>>(bb, NBUK);
    k_scatter<<<NBLK, 256, 0, stream>>>(u_idx, i_idx, E, n_u, NBUK, hist, bb, pre);
    k_place<<<NBUK, 256, 0, stream>>>(bb, n, pre, row_ptr, adj);
    k_scale_h<<<grid_for((long long)n * 32, 256, 8192), 256, 0, stream>>>(u_emb, i_emb,
                                                                          row_ptr, rnorm,
                                                                          n_u, n, xh0);

    int sblocks = (int)(((long long)n * 32 + 255) / 256);
    // layer 1: xh1 = fp16( rnorm^2 * (A_unw @ xh0) ) = rnorm .* x1   (fp16)
    k_spmm<0><<<sblocks, 256, 0, stream>>>(row_ptr, adj, rnorm, xh0, nullptr, nullptr,
                                           n_u, n, nullptr, xh1);
    // layer 2 + fused combine: out = (x0 + xh1/rnorm + rnorm*(A_unw @ xh1))/3
    k_spmm<1><<<sblocks, 256, 0, stream>>>(row_ptr, adj, rnorm, xh1, u_emb, i_emb,
                                           n_u, n, (float*)d_out, nullptr);
}